// Round 3
// baseline (449.705 us; speedup 1.0000x reference)
//
#include <hip/hip_runtime.h>

#define D_IN   2048
#define D_OUT  2048
#define N_TOK  1024
#define N_B    8
#define RANK   16
#define TPB    8          // tokens per block; 2 per wave
// SCALING = ALPHA/RANK = 16/16 = 1.0 -> omitted

__device__ __forceinline__ float dot4(float4 a, float4 b) {
    return a.x * b.x + a.y * b.y + a.z * b.z + a.w * b.w;
}

template <int CTRL>
__device__ __forceinline__ float dpp_add(float v) {
    int s = __builtin_amdgcn_update_dpp(0, __float_as_int(v), CTRL, 0xF, 0xF, true);
    return v + __int_as_float(s);
}

// 64-lane sum: 4 DPP steps (VALU pipe) + 2 shuffles. Verified correct in R2.
__device__ __forceinline__ float wave_sum(float v) {
    v = dpp_add<0xB1>(v);    // quad_perm [1,0,3,2]
    v = dpp_add<0x4E>(v);    // quad_perm [2,3,0,1]
    v = dpp_add<0x124>(v);   // row_ror:4
    v = dpp_add<0x128>(v);   // row_ror:8
    v += __shfl_xor(v, 16, 64);
    v += __shfl_xor(v, 32, 64);
    return v;
}

__global__ __launch_bounds__(256, 4)
void lora_fused_v3(const float* __restrict__ x,
                   const float* __restrict__ A,
                   const float* __restrict__ B,
                   const int* __restrict__ ids,
                   float* __restrict__ out) {
    __shared__ __align__(16) float bxs[TPB][RANK];   // 512 B handoff

    const int b    = blockIdx.y;
    const int tok0 = blockIdx.x * TPB;
    const int aid  = ids[b];
    const int tid  = threadIdx.x;
    const int wave = tid >> 6;          // wave owns tokens wave*2, wave*2+1
    const int lane = tid & 63;

    const float* __restrict__ xb = x + ((size_t)b * N_TOK + tok0 + wave * 2) * D_IN;
    const float* __restrict__ Ba = B + (size_t)aid * RANK * D_IN;
    const float* __restrict__ Aa = A + (size_t)aid * D_OUT * RANK;
    float* __restrict__ ob = out + ((size_t)b * N_TOK + tok0) * D_OUT;

    // ---------- step 1: acc[t][r] = sum_i x[t,i]*B[r,i], lanes split i ----------
    float acc0[RANK], acc1[RANK];
    #pragma unroll
    for (int r = 0; r < RANK; ++r) { acc0[r] = 0.f; acc1[r] = 0.f; }

    #pragma unroll
    for (int chunk = 0; chunk < 8; ++chunk) {
        const int ib = chunk * 256 + lane * 4;
        const float4 xv0 = *reinterpret_cast<const float4*>(&xb[ib]);
        const float4 xv1 = *reinterpret_cast<const float4*>(&xb[D_IN + ib]);
        // ranks in 2 groups of 8 to bound live registers (~90 peak)
        #pragma unroll
        for (int g = 0; g < 2; ++g) {
            float4 Bv[8];
            #pragma unroll
            for (int r = 0; r < 8; ++r)
                Bv[r] = *reinterpret_cast<const float4*>(&Ba[(size_t)(g * 8 + r) * D_IN + ib]);
            #pragma unroll
            for (int r = 0; r < 8; ++r) {
                acc0[g * 8 + r] += dot4(xv0, Bv[r]);
                acc1[g * 8 + r] += dot4(xv1, Bv[r]);
            }
        }
    }

    #pragma unroll
    for (int r = 0; r < RANK; ++r) {
        acc0[r] = wave_sum(acc0[r]);
        acc1[r] = wave_sum(acc1[r]);
    }

    if (lane == 0) {
        const int t0 = wave * 2;
        *reinterpret_cast<float4*>(&bxs[t0][0])      = make_float4(acc0[0],  acc0[1],  acc0[2],  acc0[3]);
        *reinterpret_cast<float4*>(&bxs[t0][4])      = make_float4(acc0[4],  acc0[5],  acc0[6],  acc0[7]);
        *reinterpret_cast<float4*>(&bxs[t0][8])      = make_float4(acc0[8],  acc0[9],  acc0[10], acc0[11]);
        *reinterpret_cast<float4*>(&bxs[t0][12])     = make_float4(acc0[12], acc0[13], acc0[14], acc0[15]);
        *reinterpret_cast<float4*>(&bxs[t0 + 1][0])  = make_float4(acc1[0],  acc1[1],  acc1[2],  acc1[3]);
        *reinterpret_cast<float4*>(&bxs[t0 + 1][4])  = make_float4(acc1[4],  acc1[5],  acc1[6],  acc1[7]);
        *reinterpret_cast<float4*>(&bxs[t0 + 1][8])  = make_float4(acc1[8],  acc1[9],  acc1[10], acc1[11]);
        *reinterpret_cast<float4*>(&bxs[t0 + 1][12]) = make_float4(acc1[12], acc1[13], acc1[14], acc1[15]);
    }
    __syncthreads();

    // ---------- step 2: out[t][o] = sum_r bx[t][r]*A[o][r]; A cached in regs ----------
    #pragma unroll
    for (int half = 0; half < 2; ++half) {
        const int o0 = half * 1024 + tid * 4;
        float4 Ar[4][4];
        #pragma unroll
        for (int j = 0; j < 4; ++j)
            #pragma unroll
            for (int q = 0; q < 4; ++q)
                Ar[j][q] = *reinterpret_cast<const float4*>(&Aa[(size_t)(o0 + j) * RANK + q * 4]);

        #pragma unroll
        for (int t = 0; t < TPB; ++t) {
            const float4 p0 = *reinterpret_cast<const float4*>(&bxs[t][0]);   // broadcast
            const float4 p1 = *reinterpret_cast<const float4*>(&bxs[t][4]);
            const float4 p2 = *reinterpret_cast<const float4*>(&bxs[t][8]);
            const float4 p3 = *reinterpret_cast<const float4*>(&bxs[t][12]);
            float4 res;
            res.x = dot4(Ar[0][0], p0) + dot4(Ar[0][1], p1) + dot4(Ar[0][2], p2) + dot4(Ar[0][3], p3);
            res.y = dot4(Ar[1][0], p0) + dot4(Ar[1][1], p1) + dot4(Ar[1][2], p2) + dot4(Ar[1][3], p3);
            res.z = dot4(Ar[2][0], p0) + dot4(Ar[2][1], p1) + dot4(Ar[2][2], p2) + dot4(Ar[2][3], p3);
            res.w = dot4(Ar[3][0], p0) + dot4(Ar[3][1], p1) + dot4(Ar[3][2], p2) + dot4(Ar[3][3], p3);
            *reinterpret_cast<float4*>(&ob[(size_t)t * D_OUT + o0]) = res;
        }
    }
}

extern "C" void kernel_launch(void* const* d_in, const int* in_sizes, int n_in,
                              void* d_out, int out_size, void* d_ws, size_t ws_size,
                              hipStream_t stream) {
    const float* x   = (const float*)d_in[0];
    const float* A   = (const float*)d_in[1];
    const float* B   = (const float*)d_in[2];
    const int*   ids = (const int*)d_in[3];
    float* out = (float*)d_out;

    dim3 grid(N_TOK / TPB, N_B);   // (128, 8) = 1024 blocks, 4/CU target
    lora_fused_v3<<<grid, 256, 0, stream>>>(x, A, B, ids, out);
}

// Round 4
// 148.500 us; speedup vs baseline: 3.0283x; 3.0283x over previous
//
#include <hip/hip_runtime.h>

#define D_IN   2048
#define D_OUT  2048
#define N_TOK  1024
#define N_B    8
#define RANK   16
#define TPB    8          // tokens per block; 2 per wave
// SCALING = ALPHA/RANK = 16/16 = 1.0 -> omitted

__device__ __forceinline__ float dot4(float4 a, float4 b) {
    return a.x * b.x + a.y * b.y + a.z * b.z + a.w * b.w;
}

template <int CTRL>
__device__ __forceinline__ float dpp_add(float v) {
    int s = __builtin_amdgcn_update_dpp(0, __float_as_int(v), CTRL, 0xF, 0xF, true);
    return v + __int_as_float(s);
}

// 64-lane sum: 4 DPP steps (VALU pipe) + 2 shuffles. Verified correct in R2/R3.
__device__ __forceinline__ float wave_sum(float v) {
    v = dpp_add<0xB1>(v);    // quad_perm [1,0,3,2]
    v = dpp_add<0x4E>(v);    // quad_perm [2,3,0,1]
    v = dpp_add<0x124>(v);   // row_ror:4
    v = dpp_add<0x128>(v);   // row_ror:8
    v += __shfl_xor(v, 16, 64);
    v += __shfl_xor(v, 32, 64);
    return v;
}

// NOTE: __launch_bounds__(256,4) made the compiler cap at 64 VGPRs -> ~500 MB
// scratch spill (R2/R3 post-mortem). (256,2) gave 128 VGPRs and zero spill (R1).
__global__ __launch_bounds__(256, 2)
void lora_fused_v4(const float* __restrict__ x,
                   const float* __restrict__ A,
                   const float* __restrict__ B,
                   const int* __restrict__ ids,
                   float* __restrict__ out) {
    __shared__ __align__(16) float bxs[TPB][RANK];   // 512 B handoff

    const int b    = blockIdx.y;
    const int tok0 = blockIdx.x * TPB;
    const int aid  = ids[b];
    const int tid  = threadIdx.x;
    const int wave = tid >> 6;          // wave owns tokens wave*2, wave*2+1
    const int lane = tid & 63;

    const float* __restrict__ xb = x + ((size_t)b * N_TOK + tok0 + wave * 2) * D_IN;
    const float* __restrict__ Ba = B + (size_t)aid * RANK * D_IN;
    const float* __restrict__ Aa = A + (size_t)aid * D_OUT * RANK;
    float* __restrict__ ob = out + ((size_t)b * N_TOK + tok0) * D_OUT;

    // ---------- step 1: acc[t][r] = sum_i x[t,i]*B[r,i], lanes split i ----------
    float acc0[RANK], acc1[RANK];
    #pragma unroll
    for (int r = 0; r < RANK; ++r) { acc0[r] = 0.f; acc1[r] = 0.f; }

    #pragma unroll
    for (int chunk = 0; chunk < 8; ++chunk) {
        const int ib = chunk * 256 + lane * 4;
        const float4 xv0 = *reinterpret_cast<const float4*>(&xb[ib]);
        const float4 xv1 = *reinterpret_cast<const float4*>(&xb[D_IN + ib]);
        // ranks in 2 groups of 8 to bound live registers (~95 peak)
        #pragma unroll
        for (int g = 0; g < 2; ++g) {
            float4 Bv[8];
            #pragma unroll
            for (int r = 0; r < 8; ++r)
                Bv[r] = *reinterpret_cast<const float4*>(&Ba[(size_t)(g * 8 + r) * D_IN + ib]);
            #pragma unroll
            for (int r = 0; r < 8; ++r) {
                acc0[g * 8 + r] += dot4(xv0, Bv[r]);
                acc1[g * 8 + r] += dot4(xv1, Bv[r]);
            }
        }
    }

    #pragma unroll
    for (int r = 0; r < RANK; ++r) {
        acc0[r] = wave_sum(acc0[r]);
        acc1[r] = wave_sum(acc1[r]);
    }

    if (lane == 0) {
        const int t0 = wave * 2;
        *reinterpret_cast<float4*>(&bxs[t0][0])      = make_float4(acc0[0],  acc0[1],  acc0[2],  acc0[3]);
        *reinterpret_cast<float4*>(&bxs[t0][4])      = make_float4(acc0[4],  acc0[5],  acc0[6],  acc0[7]);
        *reinterpret_cast<float4*>(&bxs[t0][8])      = make_float4(acc0[8],  acc0[9],  acc0[10], acc0[11]);
        *reinterpret_cast<float4*>(&bxs[t0][12])     = make_float4(acc0[12], acc0[13], acc0[14], acc0[15]);
        *reinterpret_cast<float4*>(&bxs[t0 + 1][0])  = make_float4(acc1[0],  acc1[1],  acc1[2],  acc1[3]);
        *reinterpret_cast<float4*>(&bxs[t0 + 1][4])  = make_float4(acc1[4],  acc1[5],  acc1[6],  acc1[7]);
        *reinterpret_cast<float4*>(&bxs[t0 + 1][8])  = make_float4(acc1[8],  acc1[9],  acc1[10], acc1[11]);
        *reinterpret_cast<float4*>(&bxs[t0 + 1][12]) = make_float4(acc1[12], acc1[13], acc1[14], acc1[15]);
    }
    __syncthreads();

    // ---------- step 2: out[t][o] = sum_r bx[t][r]*A[o][r]; A cached in regs ----------
    #pragma unroll
    for (int half = 0; half < 2; ++half) {
        const int o0 = half * 1024 + tid * 4;
        float4 Ar[4][4];
        #pragma unroll
        for (int j = 0; j < 4; ++j)
            #pragma unroll
            for (int q = 0; q < 4; ++q)
                Ar[j][q] = *reinterpret_cast<const float4*>(&Aa[(size_t)(o0 + j) * RANK + q * 4]);

        #pragma unroll
        for (int t = 0; t < TPB; ++t) {
            const float4 p0 = *reinterpret_cast<const float4*>(&bxs[t][0]);   // broadcast
            const float4 p1 = *reinterpret_cast<const float4*>(&bxs[t][4]);
            const float4 p2 = *reinterpret_cast<const float4*>(&bxs[t][8]);
            const float4 p3 = *reinterpret_cast<const float4*>(&bxs[t][12]);
            float4 res;
            res.x = dot4(Ar[0][0], p0) + dot4(Ar[0][1], p1) + dot4(Ar[0][2], p2) + dot4(Ar[0][3], p3);
            res.y = dot4(Ar[1][0], p0) + dot4(Ar[1][1], p1) + dot4(Ar[1][2], p2) + dot4(Ar[1][3], p3);
            res.z = dot4(Ar[2][0], p0) + dot4(Ar[2][1], p1) + dot4(Ar[2][2], p2) + dot4(Ar[2][3], p3);
            res.w = dot4(Ar[3][0], p0) + dot4(Ar[3][1], p1) + dot4(Ar[3][2], p2) + dot4(Ar[3][3], p3);
            *reinterpret_cast<float4*>(&ob[(size_t)t * D_OUT + o0]) = res;
        }
    }
}

extern "C" void kernel_launch(void* const* d_in, const int* in_sizes, int n_in,
                              void* d_out, int out_size, void* d_ws, size_t ws_size,
                              hipStream_t stream) {
    const float* x   = (const float*)d_in[0];
    const float* A   = (const float*)d_in[1];
    const float* B   = (const float*)d_in[2];
    const int*   ids = (const int*)d_in[3];
    float* out = (float*)d_out;

    dim3 grid(N_TOK / TPB, N_B);   // (128, 8) = 1024 blocks
    lora_fused_v4<<<grid, 256, 0, stream>>>(x, A, B, ids, out);
}